// Round 8
// baseline (32.797 us; speedup 1.0000x reference)
//
#include <hip/hip_runtime.h>
#include <math.h>

#define EPSF 1e-6f
#define NB 4
#define NR 16384
#define NS 48
#define NSEG 47
#define NRAYS (NB * NR)
#define KL 16                // lanes per ray
#define SPL 3                // samples per lane (16*3 = 48 exact)
#define RPT 4                // rays per tile == rays per wave == rays per block
#define TPB 64               // single-wave blocks: no s_barrier anywhere
#define NBLK (NRAYS / RPT)   // 16384 blocks

// LDS dword offsets (7040 B total -> 23 blocks/CU)
#define LC 0                 // colors, linear image: 4*144 = 576
#define LSM 576              // semantics, padded per-ray stride 196: 4*196 = 784
#define LD 1360              // densities, linear image: 4*48 = 192
#define LZ 1552              // depths, linear image: 4*48 = 192
#define LTOT 1760            // + pad (tail reads of t==15 stay in-bounds)
#define LW LC                // weights staging reuses colors region (188 dwords)
#define LP LSM               // partials reuse semantics region (576 dwords)

typedef const __attribute__((address_space(1))) void as1_cvoid;
typedef __attribute__((address_space(3))) void as3_void;

// fast softplus: max(x,0) + log(1+exp(-|x|)) with native exp/log
__device__ __forceinline__ float softplus_f(float x) {
    return fmaxf(x, 0.0f) + __logf(1.0f + __expf(-fabsf(x)));
}

// depths sorted along sample axis => global extrema from each ray's two ends.
// 64 blocks, each reduces 1024 rays -> ws2[bid]. ~0.5 MB of scalar gathers.
__global__ __launch_bounds__(256) void minmax_ends(const float* __restrict__ z,
                                                   float2* __restrict__ ws2) {
    __shared__ float smn[4], smx[4];
    float mn = INFINITY, mx = -INFINITY;
#pragma unroll
    for (int k = 0; k < 4; ++k) {
        const int ray = blockIdx.x * 1024 + k * 256 + threadIdx.x;
        mn = fminf(mn, z[(size_t)ray * NS]);
        mx = fmaxf(mx, z[(size_t)ray * NS + (NS - 1)]);
    }
#pragma unroll
    for (int off = 32; off > 0; off >>= 1) {
        mn = fminf(mn, __shfl_down(mn, off));
        mx = fmaxf(mx, __shfl_down(mx, off));
    }
    if ((threadIdx.x & 63) == 0) {
        smn[threadIdx.x >> 6] = mn;
        smx[threadIdx.x >> 6] = mx;
    }
    __syncthreads();
    if (threadIdx.x == 0) {
        mn = fminf(fminf(smn[0], smn[1]), fminf(smn[2], smn[3]));
        mx = fmaxf(fmaxf(smx[0], smx[1]), fmaxf(smx[2], smx[3]));
        ws2[blockIdx.x] = make_float2(mn, mx);
    }
}

__global__ __launch_bounds__(TPB, 6) void march_kernel(
    const float* __restrict__ colors, const float* __restrict__ densities,
    const float* __restrict__ depths, const float* __restrict__ semantics,
    const int* __restrict__ levels, float* __restrict__ out) {
    __shared__ float lds[LTOT];
    const int lane = threadIdx.x;
    const int r = lane >> 4;   // local ray 0..3
    const int t = lane & 15;   // owns samples 3t..3t+2 (+ boundary 3t+3)
    const int ray0 = blockIdx.x * RPT;
    const int ray = ray0 + r;
    const int lv = levels[ray >> 14];

    // ---- ALL inputs via coalesced global->LDS DMA (9 vmem ops, 0 VGPR) ----
    {   // colors: 2304B linear (2 full 1KB chunks + one quarter)
        const float* c = colors + (size_t)ray0 * 144;
        __builtin_amdgcn_global_load_lds((as1_cvoid*)(c + lane * 4),
                                         (as3_void*)(lds + LC), 16, 0, 0);
        __builtin_amdgcn_global_load_lds((as1_cvoid*)(c + 256 + lane * 4),
                                         (as3_void*)(lds + LC + 256), 16, 0, 0);
        if (lane < 16)
            __builtin_amdgcn_global_load_lds((as1_cvoid*)(c + 512 + lane * 4),
                                             (as3_void*)(lds + LC + 512), 16, 0,
                                             0);
    }
    if (lane < 48) {
        // semantics: one 768B op per ray to padded base 196*rr
#pragma unroll
        for (int rr = 0; rr < RPT; ++rr)
            __builtin_amdgcn_global_load_lds(
                (as1_cvoid*)(semantics + (size_t)(ray0 + rr) * 192 + lane * 4),
                (as3_void*)(lds + LSM + rr * 196), 16, 0, 0);
        // densities + depths: 768B linear each
        __builtin_amdgcn_global_load_lds(
            (as1_cvoid*)(densities + (size_t)ray0 * 48 + lane * 4),
            (as3_void*)(lds + LD), 16, 0, 0);
        __builtin_amdgcn_global_load_lds(
            (as1_cvoid*)(depths + (size_t)ray0 * 48 + lane * 4),
            (as3_void*)(lds + LZ), 16, 0, 0);
    }

    // single drain of the DMA queue
    asm volatile("s_waitcnt vmcnt(0)" ::: "memory");

    // ---- per-lane bases in LDS ----
    const int cb = LC + r * 144 + 9 * t;    // colors: floats 3k+{0,1,2}
    const float4* sp = (const float4*)(lds + LSM + r * 196);  // sample k = sp[3t+k]
    const int db = LD + r * 48 + 3 * t;
    const int zb = LZ + r * 48 + 3 * t;
    // t==15,k==3 tail reads land in later LDS regions / pad: in-bounds,
    // garbage, guarded-unused.

    // ---- streaming local pass with carried previous sample ----
    float pc0 = lds[cb + 0], pc1 = lds[cb + 1], pc2 = lds[cb + 2];
    float4 psm = sp[3 * t];
    float pdn = lds[db], pz = lds[zb];

    float T = 1.0f;
    float wl[SPL];
    float acc_r = 0.f, acc_g = 0.f, acc_b = 0.f, acc_d = 0.f;
    float acc_s0 = 0.f, acc_s1 = 0.f, acc_s2 = 0.f, acc_s3 = 0.f;

#pragma unroll
    for (int j = 0; j < SPL; ++j) {
        float c0 = lds[cb + 3 * (j + 1)];
        float c1 = lds[cb + 3 * (j + 1) + 1];
        float c2 = lds[cb + 3 * (j + 1) + 2];
        float4 sm4 = sp[3 * t + j + 1];
        float dn = lds[db + j + 1];
        float z = lds[zb + j + 1];

        wl[j] = 0.0f;
        if (j < 2 || t < 15) {  // lane 15 only has 2 segments (47 = 15*3 + 2)
            float delta = z - pz;
            float cm0 = (pc0 + c0) * 0.5f;
            float cm1 = (pc1 + c1) * 0.5f;
            float cm2 = (pc2 + c2) * 0.5f;
            float dnm = (pdn + dn) * 0.5f;
            float zm = (pz + z) * 0.5f;
            float sm0 = (psm.x + sm4.x) * 0.5f;
            float sm1 = (psm.y + sm4.y) * 0.5f;
            float sm2 = (psm.z + sm4.z) * 0.5f;
            float sm3 = (psm.w + sm4.w) * 0.5f;

            float sp_ = softplus_f(dnm);
            float alpha = 1.0f - __expf(-sp_ * delta);

            float factor, o0, o1, o2, o3;
            if (lv == 1) {
                factor = 1.0f - sm0;
                float inv = 1.0f / (sm1 + sm2 + sm3 + EPSF);
                o0 = 0.0f;
                o1 = (sm1 + EPSF) * inv;
                o2 = (sm2 + EPSF) * inv;
                o3 = (sm3 + EPSF) * inv;
            } else if (lv == 2) {
                factor = 1.0f - sm0 - sm3;
                float inv = 1.0f / (sm1 + sm2 + EPSF);
                o0 = 0.0f;
                o1 = (sm1 + EPSF) * inv;
                o2 = (sm2 + EPSF) * inv;
                o3 = 0.0f;
            } else {
                factor = 1.0f;
                o0 = sm0; o1 = sm1; o2 = sm2; o3 = sm3;
            }

            alpha *= factor;
            float w = alpha * T;
            T *= (1.0f - alpha + 1e-10f);
            wl[j] = w;

            acc_r += w * cm0;
            acc_g += w * cm1;
            acc_b += w * cm2;
            acc_d += w * zm;
            acc_s0 += w * o0;
            acc_s1 += w * o1;
            acc_s2 += w * o2;
            acc_s3 += w * o3;
        }
        pc0 = c0; pc1 = c1; pc2 = c2;
        psm = sm4; pdn = dn; pz = z;
    }

    // ---- inclusive product scan of local transmittance across 16 lanes ----
    float p = T;
#pragma unroll
    for (int off = 1; off < KL; off <<= 1) {
        float u = __shfl_up(p, off, KL);
        if (t >= off) p *= u;
    }
    float Tstart = __shfl_up(p, 1, KL);
    if (t == 0) Tstart = 1.0f;

    acc_r *= Tstart; acc_g *= Tstart; acc_b *= Tstart; acc_d *= Tstart;
    acc_s0 *= Tstart; acc_s1 *= Tstart; acc_s2 *= Tstart; acc_s3 *= Tstart;

    // ---- weights into consumed colors region (linear image of global) ----
#pragma unroll
    for (int j = 0; j < SPL; ++j) {
        if (j < 2 || t < 15)
            lds[LW + r * NSEG + 3 * t + j] = wl[j] * Tstart;
    }

    // ---- per-lane partials into consumed semantics region ----
    {
        const int pb = LP + r * 144 + t * 9;
        lds[pb + 0] = acc_r;  lds[pb + 1] = acc_g;
        lds[pb + 2] = acc_b;  lds[pb + 3] = acc_d;
        lds[pb + 4] = acc_s0; lds[pb + 5] = acc_s1;
        lds[pb + 6] = acc_s2; lds[pb + 7] = acc_s3;
    }

    // ---- coalesced float4 write-out of the tile's 188 weight floats ----
    if (lane < 47) {
        const float4* src = (const float4*)(lds + LW);
        float4* dst = (float4*)(out + (size_t)NRAYS * 8 + (size_t)ray0 * NSEG);
        dst[lane] = src[lane];
    }

    // ---- transposed partial reduction: lane <-> (ray rr, quantity qq) ----
    if (lane < 32) {
        const int rr = lane >> 3, qq = lane & 7;
        const int qb = LP + rr * 144 + qq;
        float v = 0.0f;
#pragma unroll
        for (int k = 0; k < KL; ++k) v += lds[qb + 9 * k];

        const int oray = ray0 + rr;
        size_t oidx;
        if (qq < 3) {
            oidx = (size_t)oray * 3 + qq;
        } else if (qq == 3) {
            if (isnan(v)) v = INFINITY;  // clip happens in clip_depth
            oidx = (size_t)NRAYS * 3 + oray;
        } else {
            oidx = (size_t)NRAYS * 4 + (size_t)oray * 4 + (qq - 4);
        }
        out[oidx] = v;
    }
}

// reduce the 64 per-block (min,max) pairs, then clip 1024 contiguous depth
// values per block with one float4 RMW per thread.
__global__ __launch_bounds__(256) void clip_depth(const float2* __restrict__ ws2,
                                                  float* __restrict__ dout) {
    __shared__ float smn[4], smx[4];
    float mn = INFINITY, mx = -INFINITY;
    if (threadIdx.x < 64) {
        float2 v = ws2[threadIdx.x];
        mn = v.x;
        mx = v.y;
    }
#pragma unroll
    for (int off = 32; off > 0; off >>= 1) {
        mn = fminf(mn, __shfl_down(mn, off));
        mx = fmaxf(mx, __shfl_down(mx, off));
    }
    if ((threadIdx.x & 63) == 0) {
        smn[threadIdx.x >> 6] = mn;
        smx[threadIdx.x >> 6] = mx;
    }
    __syncthreads();
    mn = fminf(fminf(smn[0], smn[1]), fminf(smn[2], smn[3]));
    mx = fmaxf(fmaxf(smx[0], smx[1]), fmaxf(smx[2], smx[3]));

    float4* d4 = (float4*)dout;
    const int i = blockIdx.x * 256 + threadIdx.x;  // 64 blocks * 256 = 16384
    float4 v = d4[i];
    v.x = fminf(fmaxf(v.x, mn), mx);
    v.y = fminf(fmaxf(v.y, mn), mx);
    v.z = fminf(fmaxf(v.z, mn), mx);
    v.w = fminf(fmaxf(v.w, mn), mx);
    d4[i] = v;
}

extern "C" void kernel_launch(void* const* d_in, const int* in_sizes, int n_in,
                              void* d_out, int out_size, void* d_ws, size_t ws_size,
                              hipStream_t stream) {
    const float* colors = (const float*)d_in[0];
    const float* densities = (const float*)d_in[1];
    const float* depths = (const float*)d_in[2];
    const float* semantics = (const float*)d_in[3];
    const int* levels = (const int*)d_in[4];
    float* out = (float*)d_out;
    float2* ws2 = (float2*)d_ws;  // 64 float2 = 512 B

    minmax_ends<<<64, 256, 0, stream>>>(depths, ws2);
    march_kernel<<<NBLK, TPB, 0, stream>>>(colors, densities, depths, semantics,
                                           levels, out);
    clip_depth<<<64, 256, 0, stream>>>(ws2, out + (size_t)NRAYS * 3);
}

// Round 9
// 28.876 us; speedup vs baseline: 1.1358x; 1.1358x over previous
//
#include <hip/hip_runtime.h>
#include <math.h>

#define EPSF 1e-6f
#define NB 4
#define NR 16384
#define NS 48
#define NSEG 47
#define NRAYS (NB * NR)
#define KL 16                 // lanes per ray
#define SPL 3                 // samples per lane (16*3 = 48 exact)
#define RPT 4                 // rays per tile == rays per wave
#define TPB 64                // single-wave blocks: no s_barrier anywhere
#define TPBLK 8               // tiles per block (pipelined)
#define NBLK (NRAYS / (RPT * TPBLK))  // 2048 blocks = exactly 8 per CU

// per-buffer LDS dword offsets (buffer = 1744 dwords; 2 buffers = 13952 B)
#define LC 0                  // colors, linear: 4*144 = 576
#define LSM 576               // semantics, linear: 4*192 = 768
#define LD 1344               // densities, linear: 4*48 = 192
#define LZ 1536               // depths, linear: 4*48 = 192
#define BUFSZ 1744            // 1728 + 16 pad (t==15 tail reads stay in-bounds)
#define LW LC                 // weights staging reuses colors region (188 dw)
#define LP LSM                // partials reuse semantics region (576 dw)

typedef const __attribute__((address_space(1))) void as1_cvoid;
typedef __attribute__((address_space(3))) void as3_void;

// fast softplus: max(x,0) + log(1+exp(-|x|)) with native exp/log
__device__ __forceinline__ float softplus_f(float x) {
    return fmaxf(x, 0.0f) + __logf(1.0f + __expf(-fabsf(x)));
}

// one tile's inputs -> LDS buffer: exactly 8 global_load_lds ops (~8.2 KB)
__device__ __forceinline__ void stage(const float* __restrict__ colors,
                                      const float* __restrict__ semantics,
                                      const float* __restrict__ densities,
                                      const float* __restrict__ depths,
                                      int tile, float* buf, int lane) {
    const int ray0 = tile * RPT;
    const float* c = colors + (size_t)ray0 * 144;
    __builtin_amdgcn_global_load_lds((as1_cvoid*)(c + lane * 4),
                                     (as3_void*)(buf + LC), 16, 0, 0);
    __builtin_amdgcn_global_load_lds((as1_cvoid*)(c + 256 + lane * 4),
                                     (as3_void*)(buf + LC + 256), 16, 0, 0);
    if (lane < 16)
        __builtin_amdgcn_global_load_lds((as1_cvoid*)(c + 512 + lane * 4),
                                         (as3_void*)(buf + LC + 512), 16, 0, 0);
    const float* s = semantics + (size_t)ray0 * 192;
#pragma unroll
    for (int i = 0; i < 3; ++i)
        __builtin_amdgcn_global_load_lds((as1_cvoid*)(s + i * 256 + lane * 4),
                                         (as3_void*)(buf + LSM + i * 256), 16, 0,
                                         0);
    if (lane < 48) {
        __builtin_amdgcn_global_load_lds(
            (as1_cvoid*)(densities + (size_t)ray0 * 48 + lane * 4),
            (as3_void*)(buf + LD), 16, 0, 0);
        __builtin_amdgcn_global_load_lds(
            (as1_cvoid*)(depths + (size_t)ray0 * 48 + lane * 4),
            (as3_void*)(buf + LZ), 16, 0, 0);
    }
}

// compute one staged tile; issues exactly 2 global stores
__device__ __forceinline__ void do_tile(const float* lds, int tile, int lv,
                                        float* __restrict__ out, float& gmn,
                                        float& gmx, int lane, int r, int t,
                                        float* ldsw) {
    const int ray0 = tile * RPT;

    // per-block depth extrema candidates (depths sorted per ray)
    if (lane < 4) {
        gmn = fminf(gmn, lds[LZ + lane * 48]);
        gmx = fmaxf(gmx, lds[LZ + lane * 48 + 47]);
    }

    // per-lane bases
    const int cb = LC + r * 144 + 9 * t;
    const float4* sp = (const float4*)(lds + LSM + r * 192);  // sample k = sp[3t+k]
    const int db = LD + r * 48 + 3 * t;
    const int zb = LZ + r * 48 + 3 * t;
    // t==15 tail reads land in later regions / pad: in-bounds, guarded-unused

    // streaming local pass with carried previous sample
    float pc0 = lds[cb + 0], pc1 = lds[cb + 1], pc2 = lds[cb + 2];
    float4 psm = sp[3 * t];
    float pdn = lds[db], pz = lds[zb];

    float T = 1.0f;
    float wl[SPL];
    float acc_r = 0.f, acc_g = 0.f, acc_b = 0.f, acc_d = 0.f;
    float acc_s0 = 0.f, acc_s1 = 0.f, acc_s2 = 0.f, acc_s3 = 0.f;

#pragma unroll
    for (int j = 0; j < SPL; ++j) {
        float c0 = lds[cb + 3 * (j + 1)];
        float c1 = lds[cb + 3 * (j + 1) + 1];
        float c2 = lds[cb + 3 * (j + 1) + 2];
        float4 sm4 = sp[3 * t + j + 1];
        float dn = lds[db + j + 1];
        float z = lds[zb + j + 1];

        wl[j] = 0.0f;
        if (j < 2 || t < 15) {  // lane 15 only has 2 segments (47 = 15*3+2)
            float delta = z - pz;
            float cm0 = (pc0 + c0) * 0.5f;
            float cm1 = (pc1 + c1) * 0.5f;
            float cm2 = (pc2 + c2) * 0.5f;
            float dnm = (pdn + dn) * 0.5f;
            float zm = (pz + z) * 0.5f;
            float sm0 = (psm.x + sm4.x) * 0.5f;
            float sm1 = (psm.y + sm4.y) * 0.5f;
            float sm2 = (psm.z + sm4.z) * 0.5f;
            float sm3 = (psm.w + sm4.w) * 0.5f;

            float sp_ = softplus_f(dnm);
            float alpha = 1.0f - __expf(-sp_ * delta);

            float factor, o0, o1, o2, o3;
            if (lv == 1) {
                factor = 1.0f - sm0;
                float inv = 1.0f / (sm1 + sm2 + sm3 + EPSF);
                o0 = 0.0f;
                o1 = (sm1 + EPSF) * inv;
                o2 = (sm2 + EPSF) * inv;
                o3 = (sm3 + EPSF) * inv;
            } else if (lv == 2) {
                factor = 1.0f - sm0 - sm3;
                float inv = 1.0f / (sm1 + sm2 + EPSF);
                o0 = 0.0f;
                o1 = (sm1 + EPSF) * inv;
                o2 = (sm2 + EPSF) * inv;
                o3 = 0.0f;
            } else {
                factor = 1.0f;
                o0 = sm0; o1 = sm1; o2 = sm2; o3 = sm3;
            }

            alpha *= factor;
            float w = alpha * T;
            T *= (1.0f - alpha + 1e-10f);
            wl[j] = w;

            acc_r += w * cm0;
            acc_g += w * cm1;
            acc_b += w * cm2;
            acc_d += w * zm;
            acc_s0 += w * o0;
            acc_s1 += w * o1;
            acc_s2 += w * o2;
            acc_s3 += w * o3;
        }
        pc0 = c0; pc1 = c1; pc2 = c2;
        psm = sm4; pdn = dn; pz = z;
    }

    // inclusive product scan of local transmittance across 16 lanes
    float p = T;
#pragma unroll
    for (int off = 1; off < KL; off <<= 1) {
        float u = __shfl_up(p, off, KL);
        if (t >= off) p *= u;
    }
    float Tstart = __shfl_up(p, 1, KL);
    if (t == 0) Tstart = 1.0f;

    acc_r *= Tstart; acc_g *= Tstart; acc_b *= Tstart; acc_d *= Tstart;
    acc_s0 *= Tstart; acc_s1 *= Tstart; acc_s2 *= Tstart; acc_s3 *= Tstart;

    // weights into consumed colors region (linear image of global)
#pragma unroll
    for (int j = 0; j < SPL; ++j) {
        if (j < 2 || t < 15)
            ldsw[LW + r * NSEG + 3 * t + j] = wl[j] * Tstart;
    }

    // per-lane partials into consumed semantics region
    {
        const int pb = LP + r * 144 + t * 9;
        ldsw[pb + 0] = acc_r;  ldsw[pb + 1] = acc_g;
        ldsw[pb + 2] = acc_b;  ldsw[pb + 3] = acc_d;
        ldsw[pb + 4] = acc_s0; ldsw[pb + 5] = acc_s1;
        ldsw[pb + 6] = acc_s2; ldsw[pb + 7] = acc_s3;
    }

    // coalesced float4 write-out of the tile's 188 weight floats (store #1)
    if (lane < 47) {
        const float4* src = (const float4*)(lds + LW);
        float4* dst = (float4*)(out + (size_t)NRAYS * 8 + (size_t)ray0 * NSEG);
        dst[lane] = src[lane];
    }

    // transposed partial reduction: lane <-> (ray rr, quantity qq) (store #2)
    if (lane < 32) {
        const int rr = lane >> 3, qq = lane & 7;
        const int qb = LP + rr * 144 + qq;
        float v = 0.0f;
#pragma unroll
        for (int k = 0; k < KL; ++k) v += lds[qb + 9 * k];

        const int oray = ray0 + rr;
        size_t oidx;
        if (qq < 3) {
            oidx = (size_t)oray * 3 + qq;
        } else if (qq == 3) {
            if (isnan(v)) v = INFINITY;  // clip happens in clip_depth
            oidx = (size_t)NRAYS * 3 + oray;
        } else {
            oidx = (size_t)NRAYS * 4 + (size_t)oray * 4 + (qq - 4);
        }
        out[oidx] = v;
    }
}

__global__ __launch_bounds__(TPB) void march_kernel(
    const float* __restrict__ colors, const float* __restrict__ densities,
    const float* __restrict__ depths, const float* __restrict__ semantics,
    const int* __restrict__ levels, float2* __restrict__ ws2,
    float* __restrict__ out) {
    __shared__ float lds[2 * BUFSZ];
    const int lane = threadIdx.x;
    const int r = lane >> 4;   // local ray 0..3
    const int t = lane & 15;   // owns samples 3t..3t+2 (+ boundary)
    const int tile0 = blockIdx.x * TPBLK;
    // block covers 32 consecutive rays -> single batch -> uniform level
    const int lv = levels[(tile0 * RPT) >> 14];
    float gmn = INFINITY, gmx = -INFINITY;

    // ---- software pipeline: DMA(k+1) in flight while computing tile k ----
    stage(colors, semantics, densities, depths, tile0, lds, lane);

    // iter 0
    stage(colors, semantics, densities, depths, tile0 + 1, lds + BUFSZ, lane);
    asm volatile("" ::: "memory");            // pin stage before the wait
    asm volatile("s_waitcnt vmcnt(8)" ::: "memory");  // tile0 staged; 8 in flight
    do_tile(lds, tile0, lv, out, gmn, gmx, lane, r, t, lds);

    // iters 1..6: steady state, vmcnt(10) = next-tile DMA(8) + prev stores(2)
#pragma unroll 2
    for (int k = 1; k < TPBLK - 1; ++k) {
        float* nbuf = lds + (((k + 1) & 1) ? BUFSZ : 0);
        float* cbuf = lds + ((k & 1) ? BUFSZ : 0);
        stage(colors, semantics, densities, depths, tile0 + k + 1, nbuf, lane);
        asm volatile("" ::: "memory");
        asm volatile("s_waitcnt vmcnt(10)" ::: "memory");
        do_tile(cbuf, tile0 + k, lv, out, gmn, gmx, lane, r, t, cbuf);
    }

    // iter 7: drain to the last tile's stores only
    asm volatile("s_waitcnt vmcnt(2)" ::: "memory");
    do_tile(lds + BUFSZ, tile0 + TPBLK - 1, lv, out, gmn, gmx, lane, r, t,
            lds + BUFSZ);

    // ---- block depth extrema (reduce lanes 0..3) ----
    gmn = fminf(gmn, __shfl_xor(gmn, 1, 4));
    gmn = fminf(gmn, __shfl_xor(gmn, 2, 4));
    gmx = fmaxf(gmx, __shfl_xor(gmx, 1, 4));
    gmx = fmaxf(gmx, __shfl_xor(gmx, 2, 4));
    if (lane == 0) ws2[blockIdx.x] = make_float2(gmn, gmx);
}

// reduce the 2048 per-block (min,max) pairs, then clip 1024 contiguous depth
// values per block with one float4 RMW per thread.
__global__ __launch_bounds__(256) void clip_depth(const float2* __restrict__ ws2,
                                                  float* __restrict__ dout) {
    __shared__ float smn[4], smx[4];
    float mn = INFINITY, mx = -INFINITY;
#pragma unroll
    for (int k = 0; k < NBLK / 256; ++k) {
        float2 v = ws2[threadIdx.x + (k << 8)];
        mn = fminf(mn, v.x);
        mx = fmaxf(mx, v.y);
    }
#pragma unroll
    for (int off = 32; off > 0; off >>= 1) {
        mn = fminf(mn, __shfl_down(mn, off));
        mx = fmaxf(mx, __shfl_down(mx, off));
    }
    if ((threadIdx.x & 63) == 0) {
        smn[threadIdx.x >> 6] = mn;
        smx[threadIdx.x >> 6] = mx;
    }
    __syncthreads();
    mn = fminf(fminf(smn[0], smn[1]), fminf(smn[2], smn[3]));
    mx = fmaxf(fmaxf(smx[0], smx[1]), fmaxf(smx[2], smx[3]));

    float4* d4 = (float4*)dout;
    const int i = blockIdx.x * 256 + threadIdx.x;  // 64 blocks * 256 = 16384
    float4 v = d4[i];
    v.x = fminf(fmaxf(v.x, mn), mx);
    v.y = fminf(fmaxf(v.y, mn), mx);
    v.z = fminf(fmaxf(v.z, mn), mx);
    v.w = fminf(fmaxf(v.w, mn), mx);
    d4[i] = v;
}

extern "C" void kernel_launch(void* const* d_in, const int* in_sizes, int n_in,
                              void* d_out, int out_size, void* d_ws, size_t ws_size,
                              hipStream_t stream) {
    const float* colors = (const float*)d_in[0];
    const float* densities = (const float*)d_in[1];
    const float* depths = (const float*)d_in[2];
    const float* semantics = (const float*)d_in[3];
    const int* levels = (const int*)d_in[4];
    float* out = (float*)d_out;
    float2* ws2 = (float2*)d_ws;  // 2048 float2 = 16 KB

    march_kernel<<<NBLK, TPB, 0, stream>>>(colors, densities, depths, semantics,
                                           levels, ws2, out);
    clip_depth<<<64, 256, 0, stream>>>(ws2, out + (size_t)NRAYS * 3);
}